// Round 4
// baseline (1033.144 us; speedup 1.0000x reference)
//
#include <hip/hip_runtime.h>

#define NBLK 128
#define NTHR 256

typedef __bf16 bf16x8 __attribute__((ext_vector_type(8)));
typedef float  f32x4  __attribute__((ext_vector_type(4)));

__device__ __forceinline__ unsigned short f2bf(float f) {
  unsigned int u = __float_as_uint(f);
  return (unsigned short)((u + 0x7fffu + ((u >> 16) & 1u)) >> 16);  // RNE
}

__device__ __forceinline__ bf16x8 asbf(uint4 u) {
  return __builtin_bit_cast(bf16x8, u);
}

__device__ __forceinline__ float sigf(float xv) { return 1.0f / (1.0f + __expf(-xv)); }

// ws layout (bytes):
//   OUTB  bf16 [2][32][1024]     parity ping-pong of cell input    131072
//   HBB   bf16 [2][2][32][1024]  [t-parity][layer] h for GEMM      262144
//   SSE   f32
//   BARC  int                    grid barrier counter (monotonic)
#define WS_OUTB 0
#define WS_HBB  131072
#define WS_SSE  (131072 + 262144)
#define WS_BARC (WS_SSE + 4)

// ---------------- prep: init activations + counters ----------------
__global__ void prep_kernel(const float* __restrict__ x, const float* __restrict__ h0,
                            unsigned char* __restrict__ ws)
{
  unsigned short* outb = (unsigned short*)(ws + WS_OUTB);
  unsigned short* hbb  = (unsigned short*)(ws + WS_HBB);
  int gid = blockIdx.x * blockDim.x + threadIdx.x;
  int stride = gridDim.x * blockDim.x;
  for (int i = gid; i < 32768; i += stride) outb[i] = f2bf(x[i]);   // parity 0 = x
  for (int i = gid; i < 65536; i += stride) hbb[i]  = f2bf(h0[i]);  // t-parity 0, both layers
  if (gid == 0) {
    *(float*)(ws + WS_SSE) = 0.0f;
    *(int*)(ws + WS_BARC) = 0;
  }
}

// ---------------- persistent kernel: all 32 cells, weights in registers ----------------
__global__ void __launch_bounds__(NTHR, 1)
persist_kernel(const float* __restrict__ h0, const float* __restrict__ c0,
               const float* __restrict__ hmask, const float* __restrict__ cmask,
               const float* __restrict__ labels,
               const float* __restrict__ Wih, const float* __restrict__ Whh,
               const float* __restrict__ bih, const float* __restrict__ bhh,
               float* __restrict__ out, unsigned char* __restrict__ ws)
{
  const int tid = threadIdx.x;
  const int bid = blockIdx.x;
  const int l   = bid >> 6;          // layer this block owns
  const int g   = bid & 63;          // 16-col group

  unsigned short* outb = (unsigned short*)(ws + WS_OUTB);
  unsigned short* hbb  = (unsigned short*)(ws + WS_HBB);
  float*          sse  = (float*)(ws + WS_SSE);
  int*            barc = (int*)(ws + WS_BARC);

  __shared__ __align__(16) unsigned short As[32 * 520];   // A chunk 32x512, +8 pad
  __shared__ float Ps[4 * 544];                           // [gate][m*17 + c]

  const int lane = tid & 63;
  const int w    = tid >> 6;         // wave = gate
  const int q    = lane >> 4;
  const int m0   = lane & 15;

  // ---- one-time: load this wave's B-slice [16 cols x 2048] into 256 VGPRs (bf16) ----
  const size_t wro = (size_t)(l * 4096 + w * 1024 + g * 16 + m0) * 1024;
  const float* wihr = Wih + wro;
  const float* whhr = Whh + wro;
  uint4 bw[64];
#pragma unroll
  for (int ks = 0; ks < 64; ++ks) {
    int k = ks * 32 + q * 8;         // k within 2048 concat [Wih | Whh]
    const float* src = (k < 1024) ? (wihr + k) : (whhr + (k - 1024));
    float4 f0 = *(const float4*)src;
    float4 f1 = *(const float4*)(src + 4);
    uint4 u;
    u.x = (unsigned)f2bf(f0.x) | ((unsigned)f2bf(f0.y) << 16);
    u.y = (unsigned)f2bf(f0.z) | ((unsigned)f2bf(f0.w) << 16);
    u.z = (unsigned)f2bf(f1.x) | ((unsigned)f2bf(f1.y) << 16);
    u.w = (unsigned)f2bf(f1.z) | ((unsigned)f2bf(f1.w) << 16);
    bw[ks] = u;
  }

  // ---- per-thread persistent fp32 state + combined bias ----
  const int c_ = tid & 15;
  const int ma = tid >> 4;
  const int jg = g * 16 + c_;
  float hsr0 = h0[(l * 32 + ma) * 1024 + jg];
  float hsr1 = h0[(l * 32 + ma + 16) * 1024 + jg];
  float csr0 = c0[(l * 32 + ma) * 1024 + jg];
  float csr1 = c0[(l * 32 + ma + 16) * 1024 + jg];
  float bv[4];
#pragma unroll
  for (int gt = 0; gt < 4; ++gt) {
    int n = l * 4096 + gt * 1024 + jg;
    bv[gt] = bih[n] + bhh[n];
  }
  float local_sse = 0.0f;
  const int r_s = tid >> 3, seg = tid & 7;

  for (int ci = 0; ci < 32; ++ci) {
    const int t = ci >> 1;
    if ((ci & 1) == l) {
      // ---------- GEMM: gates[4][32][16] = A[32x2048] * B^T, B in regs ----------
      const unsigned short* outc = outb + l * 32768;
      const unsigned short* hbc  = hbb + ((t & 1) * 2 + l) * 32768;
      f32x4 acc0 = {0.f,0.f,0.f,0.f}, acc1 = {0.f,0.f,0.f,0.f};
      uint4 stg[8];
      {
        const unsigned short* sp = outc + r_s * 1024;
#pragma unroll
        for (int it = 0; it < 8; ++it) stg[it] = *(const uint4*)(sp + seg * 64 + it * 8);
      }
#pragma unroll
      for (int kc = 0; kc < 4; ++kc) {
        __syncthreads();
#pragma unroll
        for (int it = 0; it < 8; ++it)
          *(uint4*)&As[r_s * 520 + seg * 64 + it * 8] = stg[it];
        __syncthreads();
        if (kc < 3) {
          int kn = kc + 1;
          const unsigned short* sp = (kn < 2) ? (outc + r_s * 1024 + kn * 512)
                                              : (hbc  + r_s * 1024 + (kn - 2) * 512);
#pragma unroll
          for (int it = 0; it < 8; ++it) stg[it] = *(const uint4*)(sp + seg * 64 + it * 8);
        }
#pragma unroll
        for (int ks = 0; ks < 16; ++ks) {
          int kl = ks * 32 + q * 8;
          bf16x8 a0 = asbf(*(const uint4*)&As[m0 * 520 + kl]);
          bf16x8 a1 = asbf(*(const uint4*)&As[(m0 + 16) * 520 + kl]);
          bf16x8 b  = asbf(bw[kc * 16 + ks]);
          acc0 = __builtin_amdgcn_mfma_f32_16x16x32_bf16(a0, b, acc0, 0, 0, 0);
          acc1 = __builtin_amdgcn_mfma_f32_16x16x32_bf16(a1, b, acc1, 0, 0, 0);
        }
      }
      // ---------- cross-wave gate exchange (no atomics: full K per block) ----------
#pragma unroll
      for (int i = 0; i < 4; ++i) {
        int r0 = q * 4 + i;            // C/D: row = quad*4+reg, col = lane&15
        Ps[w * 544 + r0 * 17 + m0]        = acc0[i];
        Ps[w * 544 + (r0 + 16) * 17 + m0] = acc1[i];
      }
      __syncthreads();
      // ---------- pointwise: LSTM + zoneout, state in registers ----------
      int mbase = ((t * 2 + l) * 32 + ma) * 1024 + jg;
      float hm0v = hmask[mbase], hm1v = hmask[mbase + 16384];
      float cm0v = cmask[mbase], cm1v = cmask[mbase + 16384];
#pragma unroll
      for (int hf = 0; hf < 2; ++hf) {
        int m = ma + hf * 16;
        float gi = Ps[0 * 544 + m * 17 + c_] + bv[0];
        float gf = Ps[1 * 544 + m * 17 + c_] + bv[1];
        float gg = Ps[2 * 544 + m * 17 + c_] + bv[2];
        float go = Ps[3 * 544 + m * 17 + c_] + bv[3];
        float ii = sigf(gi), ff = sigf(gf), oo = sigf(go);
        float gt = tanhf(gg);
        float cprev = hf ? csr1 : csr0;
        float hprev = hf ? hsr1 : hsr0;
        float ccand = ff * cprev + ii * gt;
        float hcand = oo * tanhf(ccand);
        float hmv = hf ? hm1v : hm0v;
        float cmv = hf ? cm1v : cm0v;
        float hnew = hmv * hprev + (1.0f - hmv) * hcand;
        float cnew = cmv * cprev + (1.0f - cmv) * ccand;
        if (hf) { csr1 = cnew; hsr1 = hnew; } else { csr0 = cnew; hsr0 = hnew; }
        unsigned short ub = f2bf(hnew);
        outb[(l ^ 1) * 32768 + m * 1024 + jg] = ub;                 // next cell's input
        hbb[(((t + 1) & 1) * 2 + l) * 32768 + m * 1024 + jg] = ub;  // next t, same layer
        if (l == 1) {
          out[(m * 16 + t) * 1024 + jg] = hnew;                     // ret[b][t][h]
          float d = hnew - labels[(m * 16 + t) * 1024 + jg];
          local_sse += d * d;
        }
      }
    }
    // ---------- grid barrier (monotonic counter, agent scope) ----------
    __syncthreads();                   // drains all waves' vmcnt (stores in L2)
    if (tid == 0) {
      __threadfence();                 // agent fence: L2 writeback
      __hip_atomic_fetch_add(barc, 1, __ATOMIC_RELAXED, __HIP_MEMORY_SCOPE_AGENT);
      const int tgt = NBLK * (ci + 1);
      while (__hip_atomic_load(barc, __ATOMIC_RELAXED, __HIP_MEMORY_SCOPE_AGENT) < tgt)
        __builtin_amdgcn_s_sleep(1);
      __threadfence();                 // agent fence: L1/L2 invalidate
    }
    __syncthreads();
  }

  // ---------------- loss ----------------
  if (l == 1) {
    float s = local_sse;
#pragma unroll
    for (int off = 32; off > 0; off >>= 1) s += __shfl_down(s, off);
    if (lane == 0)
      __hip_atomic_fetch_add(sse, s, __ATOMIC_RELAXED, __HIP_MEMORY_SCOPE_AGENT);
  }
  __syncthreads();
  if (tid == 0) {
    __threadfence();
    __hip_atomic_fetch_add(barc, 1, __ATOMIC_RELAXED, __HIP_MEMORY_SCOPE_AGENT);
    while (__hip_atomic_load(barc, __ATOMIC_RELAXED, __HIP_MEMORY_SCOPE_AGENT) < NBLK * 33)
      __builtin_amdgcn_s_sleep(1);
    __threadfence();
  }
  __syncthreads();
  if (bid == 64 && tid == 0)
    out[524288] = __hip_atomic_load(sse, __ATOMIC_RELAXED, __HIP_MEMORY_SCOPE_AGENT)
                  * (1.0f / 524288.0f);
}

extern "C" void kernel_launch(void* const* d_in, const int* in_sizes, int n_in,
                              void* d_out, int out_size, void* d_ws, size_t ws_size,
                              hipStream_t stream) {
  (void)in_sizes; (void)n_in; (void)out_size; (void)ws_size;
  const float* x   = (const float*)d_in[0];
  const float* h0  = (const float*)d_in[1];
  const float* c0  = (const float*)d_in[2];
  const float* hm  = (const float*)d_in[3];
  const float* cm  = (const float*)d_in[4];
  const float* lb  = (const float*)d_in[5];
  const float* wih = (const float*)d_in[6];
  const float* whh = (const float*)d_in[7];
  const float* bi  = (const float*)d_in[8];
  const float* bh  = (const float*)d_in[9];
  float* out = (float*)d_out;
  unsigned char* ws = (unsigned char*)d_ws;

  prep_kernel<<<dim3(256), dim3(256), 0, stream>>>(x, h0, ws);
  persist_kernel<<<dim3(NBLK), dim3(NTHR), 0, stream>>>(h0, c0, hm, cm, lb,
                                                        wih, whh, bi, bh, out, ws);
}

// Round 5
// 811.803 us; speedup vs baseline: 1.2727x; 1.2727x over previous
//
#include <hip/hip_runtime.h>

#define NBLK 128
#define NTHR 512

typedef __bf16 bf16x8 __attribute__((ext_vector_type(8)));
typedef float  f32x4  __attribute__((ext_vector_type(4)));

__device__ __forceinline__ unsigned short f2bf(float f) {
  unsigned int u = __float_as_uint(f);
  return (unsigned short)((u + 0x7fffu + ((u >> 16) & 1u)) >> 16);  // RNE
}

__device__ __forceinline__ bf16x8 asbf(uint4 u) {
  return __builtin_bit_cast(bf16x8, u);
}

__device__ __forceinline__ float sigf(float xv) { return 1.0f / (1.0f + __expf(-xv)); }

// ws layout (bytes):
//   OUTB  bf16 [2][32][1024]     parity ping-pong of cell input    131072
//   HBB   bf16 [2][2][32][1024]  [t-parity][layer] h for GEMM      262144
//   SSE   f32
//   BARC  int                    grid barrier counter (monotonic)
#define WS_OUTB 0
#define WS_HBB  131072
#define WS_SSE  (131072 + 262144)
#define WS_BARC (WS_SSE + 4)

// ---------------- prep: init activations + counters ----------------
__global__ void prep_kernel(const float* __restrict__ x, const float* __restrict__ h0,
                            unsigned char* __restrict__ ws)
{
  unsigned short* outb = (unsigned short*)(ws + WS_OUTB);
  unsigned short* hbb  = (unsigned short*)(ws + WS_HBB);
  int gid = blockIdx.x * blockDim.x + threadIdx.x;
  int stride = gridDim.x * blockDim.x;
  for (int i = gid; i < 32768; i += stride) outb[i] = f2bf(x[i]);   // parity 0 = x
  for (int i = gid; i < 65536; i += stride) hbb[i]  = f2bf(h0[i]);  // t-parity 0, both layers
  if (gid == 0) {
    *(float*)(ws + WS_SSE) = 0.0f;
    *(int*)(ws + WS_BARC) = 0;
  }
}

// ---------------- persistent kernel: all 32 cells, weights in registers ----------------
// 128 blocks x 512 threads. Block (l, g): 16 H-cols of one layer.
// 8 waves = (gate, K-half): bw[32] uint4 = 128 VGPRs of bf16 weights per lane.
__global__ void __launch_bounds__(NTHR, 2)
persist_kernel(const float* __restrict__ h0, const float* __restrict__ c0,
               const float* __restrict__ hmask, const float* __restrict__ cmask,
               const float* __restrict__ labels,
               const float* __restrict__ Wih, const float* __restrict__ Whh,
               const float* __restrict__ bih, const float* __restrict__ bhh,
               float* __restrict__ out, unsigned char* __restrict__ ws)
{
  const int tid = threadIdx.x;
  const int bid = blockIdx.x;
  const int l   = bid >> 6;          // layer this block owns
  const int g   = bid & 63;          // 16-col group

  unsigned short* outb = (unsigned short*)(ws + WS_OUTB);
  unsigned short* hbb  = (unsigned short*)(ws + WS_HBB);
  float*          sse  = (float*)(ws + WS_SSE);
  int*            barc = (int*)(ws + WS_BARC);

  __shared__ __align__(16) unsigned short As[32 * 520];   // A chunk 32x512, +8 pad (33280 B)
  __shared__ float Ps[8 * 544];                           // [khalf][gate][m*17 + c] (17408 B)

  const int lane = tid & 63;
  const int w    = tid >> 6;         // 0..7
  const int gate = w & 3;
  const int kh   = w >> 2;           // K-half (1024) this wave owns
  const int q    = lane >> 4;
  const int m0   = lane & 15;

  // ---- one-time: this wave's B-slice [16 cols x 1024 K] -> 128 VGPRs bf16 ----
  // k = kh*1024 + idx*32 + q*8 ; kh=0 -> Wih, kh=1 -> Whh (wave-uniform select)
  const size_t wro = (size_t)(l * 4096 + gate * 1024 + g * 16 + m0) * 1024;
  const float* wbase = (kh == 0) ? (Wih + wro) : (Whh + wro);
  uint4 bw[32];
#pragma unroll
  for (int idx = 0; idx < 32; ++idx) {
    const float* src = wbase + idx * 32 + q * 8;
    float4 f0 = *(const float4*)src;
    float4 f1 = *(const float4*)(src + 4);
    uint4 u;
    u.x = (unsigned)f2bf(f0.x) | ((unsigned)f2bf(f0.y) << 16);
    u.y = (unsigned)f2bf(f0.z) | ((unsigned)f2bf(f0.w) << 16);
    u.z = (unsigned)f2bf(f1.x) | ((unsigned)f2bf(f1.y) << 16);
    u.w = (unsigned)f2bf(f1.z) | ((unsigned)f2bf(f1.w) << 16);
    bw[idx] = u;
  }

  // ---- per-thread persistent fp32 state + combined bias (one (m, col) per thread) ----
  const int c_ = tid & 15;
  const int ma = tid >> 4;           // 0..31
  const int jg = g * 16 + c_;
  float hsr = h0[(l * 32 + ma) * 1024 + jg];
  float csr = c0[(l * 32 + ma) * 1024 + jg];
  float bv[4];
#pragma unroll
  for (int gt = 0; gt < 4; ++gt) {
    int n = l * 4096 + gt * 1024 + jg;
    bv[gt] = bih[n] + bhh[n];
  }
  float local_sse = 0.0f;
  const int r_s = tid >> 4, seg = tid & 15;   // staging: row 0..31, 16 segs of 32 k

  for (int ci = 0; ci < 32; ++ci) {
    const int t = ci >> 1;
    if ((ci & 1) == l) {
      // ---------- GEMM: gates[4][32][16] = A[32x2048] * B^T, B in regs ----------
      const unsigned short* outc = outb + l * 32768;
      const unsigned short* hbc  = hbb + ((t & 1) * 2 + l) * 32768;
      f32x4 acc0 = {0.f,0.f,0.f,0.f}, acc1 = {0.f,0.f,0.f,0.f};
      uint4 stg[4];
      {
        const unsigned short* sp = outc + r_s * 1024 + seg * 32;
#pragma unroll
        for (int it = 0; it < 4; ++it) stg[it] = *(const uint4*)(sp + it * 8);
      }
#pragma unroll
      for (int kc = 0; kc < 4; ++kc) {
        __syncthreads();
#pragma unroll
        for (int it = 0; it < 4; ++it)
          *(uint4*)&As[r_s * 520 + seg * 32 + it * 8] = stg[it];
        __syncthreads();
        if (kc < 3) {
          int kn = kc + 1;
          const unsigned short* sp = (kn < 2) ? (outc + r_s * 1024 + kn * 512 + seg * 32)
                                              : (hbc  + r_s * 1024 + (kn - 2) * 512 + seg * 32);
#pragma unroll
          for (int it = 0; it < 4; ++it) stg[it] = *(const uint4*)(sp + it * 8);
        }
        if ((kc >> 1) == kh) {
#pragma unroll
          for (int ks = 0; ks < 16; ++ks) {
            int kl = ks * 32 + q * 8;
            bf16x8 a0 = asbf(*(const uint4*)&As[m0 * 520 + kl]);
            bf16x8 a1 = asbf(*(const uint4*)&As[(m0 + 16) * 520 + kl]);
            bf16x8 b  = asbf(bw[(kc & 1) * 16 + ks]);
            acc0 = __builtin_amdgcn_mfma_f32_16x16x32_bf16(a0, b, acc0, 0, 0, 0);
            acc1 = __builtin_amdgcn_mfma_f32_16x16x32_bf16(a1, b, acc1, 0, 0, 0);
          }
        }
      }
      // ---------- gate exchange: plain LDS stores, [khalf][gate] slots ----------
#pragma unroll
      for (int i = 0; i < 4; ++i) {
        int r0 = q * 4 + i;            // C/D: row = quad*4+reg, col = lane&15
        Ps[(kh * 4 + gate) * 544 + r0 * 17 + m0]        = acc0[i];
        Ps[(kh * 4 + gate) * 544 + (r0 + 16) * 17 + m0] = acc1[i];
      }
      __syncthreads();
      // ---------- pointwise: LSTM + zoneout, one element per thread ----------
      int mbase = ((t * 2 + l) * 32 + ma) * 1024 + jg;
      float hmv = hmask[mbase];
      float cmv = cmask[mbase];
      float gi = Ps[(0 + 0) * 544 + ma * 17 + c_] + Ps[(4 + 0) * 544 + ma * 17 + c_] + bv[0];
      float gf = Ps[(0 + 1) * 544 + ma * 17 + c_] + Ps[(4 + 1) * 544 + ma * 17 + c_] + bv[1];
      float gg = Ps[(0 + 2) * 544 + ma * 17 + c_] + Ps[(4 + 2) * 544 + ma * 17 + c_] + bv[2];
      float go = Ps[(0 + 3) * 544 + ma * 17 + c_] + Ps[(4 + 3) * 544 + ma * 17 + c_] + bv[3];
      float ii = sigf(gi), ff = sigf(gf), oo = sigf(go);
      float gt = tanhf(gg);
      float ccand = ff * csr + ii * gt;
      float hcand = oo * tanhf(ccand);
      float hnew = hmv * hsr + (1.0f - hmv) * hcand;
      float cnew = cmv * csr + (1.0f - cmv) * ccand;
      csr = cnew; hsr = hnew;
      unsigned short ub = f2bf(hnew);
      outb[(l ^ 1) * 32768 + ma * 1024 + jg] = ub;                 // next cell's input
      hbb[(((t + 1) & 1) * 2 + l) * 32768 + ma * 1024 + jg] = ub;  // next t, same layer
      if (l == 1) {
        out[(ma * 16 + t) * 1024 + jg] = hnew;                     // ret[b][t][h]
        float d = hnew - labels[(ma * 16 + t) * 1024 + jg];
        local_sse += d * d;
      }
    }
    // ---------- grid barrier (monotonic counter, agent scope; proven in R4) ----------
    __syncthreads();                   // drains all waves' vmcnt (stores in L2)
    if (tid == 0) {
      __threadfence();                 // release: L2 writeback (device scope)
      __hip_atomic_fetch_add(barc, 1, __ATOMIC_RELAXED, __HIP_MEMORY_SCOPE_AGENT);
      const int tgt = NBLK * (ci + 1);
      while (__hip_atomic_load(barc, __ATOMIC_RELAXED, __HIP_MEMORY_SCOPE_AGENT) < tgt)
        __builtin_amdgcn_s_sleep(1);
      __threadfence();                 // acquire: L1 invalidate (per-CU, covers block)
    }
    __syncthreads();
  }

  // ---------------- loss ----------------
  if (l == 1) {
    float s = local_sse;
#pragma unroll
    for (int off = 32; off > 0; off >>= 1) s += __shfl_down(s, off);
    if (lane == 0)
      __hip_atomic_fetch_add(sse, s, __ATOMIC_RELAXED, __HIP_MEMORY_SCOPE_AGENT);
  }
  __syncthreads();
  if (tid == 0) {
    __threadfence();
    __hip_atomic_fetch_add(barc, 1, __ATOMIC_RELAXED, __HIP_MEMORY_SCOPE_AGENT);
    while (__hip_atomic_load(barc, __ATOMIC_RELAXED, __HIP_MEMORY_SCOPE_AGENT) < NBLK * 33)
      __builtin_amdgcn_s_sleep(1);
    __threadfence();
  }
  __syncthreads();
  if (bid == 64 && tid == 0)
    out[524288] = __hip_atomic_load(sse, __ATOMIC_RELAXED, __HIP_MEMORY_SCOPE_AGENT)
                  * (1.0f / 524288.0f);
}

extern "C" void kernel_launch(void* const* d_in, const int* in_sizes, int n_in,
                              void* d_out, int out_size, void* d_ws, size_t ws_size,
                              hipStream_t stream) {
  (void)in_sizes; (void)n_in; (void)out_size; (void)ws_size;
  const float* x   = (const float*)d_in[0];
  const float* h0  = (const float*)d_in[1];
  const float* c0  = (const float*)d_in[2];
  const float* hm  = (const float*)d_in[3];
  const float* cm  = (const float*)d_in[4];
  const float* lb  = (const float*)d_in[5];
  const float* wih = (const float*)d_in[6];
  const float* whh = (const float*)d_in[7];
  const float* bi  = (const float*)d_in[8];
  const float* bh  = (const float*)d_in[9];
  float* out = (float*)d_out;
  unsigned char* ws = (unsigned char*)d_ws;

  prep_kernel<<<dim3(256), dim3(256), 0, stream>>>(x, h0, ws);
  persist_kernel<<<dim3(NBLK), dim3(NTHR), 0, stream>>>(h0, c0, hm, cm, lb,
                                                        wih, whh, bi, bh, out, ws);
}